// Round 1
// baseline (3384.639 us; speedup 1.0000x reference)
//
#include <hip/hip_runtime.h>
#include <math.h>

// Problem constants (from setup_inputs): x [8,3,384,1280] f32,
// flow [8,2,384,1280] f32, depth [8,1,384,1280] f32 -> out [8,3,384,1280] f32.
#define BB 8
#define CC 3
#define HH 384
#define WW 1280
#define HW (HH * WW)

// Splat: one thread per source pixel (b, h, w).
// Accumulators: xw_acc = d_out [B,3,H,W]; dw_acc, mask_acc in ws [B,H,W] each.
__global__ __launch_bounds__(256) void splat_kernel(
    const float* __restrict__ x, const float* __restrict__ flow,
    const float* __restrict__ depth, float* __restrict__ xw_acc,
    float* __restrict__ dw_acc, float* __restrict__ mask_acc) {
  int idx = blockIdx.x * blockDim.x + threadIdx.x;
  if (idx >= BB * HW) return;
  int b = idx / HW;
  int p = idx - b * HW;
  int h = p / WW;
  int w = p - h * WW;

  float fx = flow[(b * 2 + 0) * HW + p];
  float fy = flow[(b * 2 + 1) * HW + p];
  fx = fminf(fmaxf(fx, -2.0f * WW), 2.0f * WW);
  fy = fminf(fmaxf(fy, -2.0f * WW), 2.0f * WW);

  float xs = fx + (float)w;
  float ys = fy + (float)h;
  float x0 = floorf(xs);
  float y0 = floorf(ys);
  // valid iff whole 2x2 footprint inside: x0>=0, x0+1<=W-1, y0>=0, y0+1<=H-1
  if (!(x0 >= 0.0f && x0 <= (float)(WW - 2) && y0 >= 0.0f && y0 <= (float)(HH - 2)))
    return;
  int x0i = (int)x0;
  int y0i = (int)y0;
  float ax = xs - x0;   // in [0,1)
  float ay = ys - y0;
  float w_nw = (1.0f - ax) * (1.0f - ay);
  float w_ne = ax * (1.0f - ay);
  float w_sw = (1.0f - ax) * ay;
  float w_se = ax * ay;

  float d = depth[b * HW + p];
  d = fminf(fmaxf(d, 0.001f), 80.0f);
  float dw = expf(-(d - 40.0f) * (1.0f / 5.0f));

  float xv0 = x[(b * CC + 0) * HW + p] * dw;
  float xv1 = x[(b * CC + 1) * HW + p] * dw;
  float xv2 = x[(b * CC + 2) * HW + p] * dw;

  float* dwb = dw_acc + b * HW;
  float* mkb = mask_acc + b * HW;
  float* xb0 = xw_acc + (b * CC + 0) * HW;
  float* xb1 = xw_acc + (b * CC + 1) * HW;
  float* xb2 = xw_acc + (b * CC + 2) * HW;

  int i_nw = y0i * WW + x0i;
  int i_ne = i_nw + 1;
  int i_sw = i_nw + WW;
  int i_se = i_sw + 1;

#define SPLAT(ci, wt)                    \
  do {                                   \
    atomicAdd(dwb + (ci), (wt) * dw);    \
    atomicAdd(mkb + (ci), (wt));         \
    atomicAdd(xb0 + (ci), (wt) * xv0);   \
    atomicAdd(xb1 + (ci), (wt) * xv1);   \
    atomicAdd(xb2 + (ci), (wt) * xv2);   \
  } while (0)

  SPLAT(i_nw, w_nw);
  SPLAT(i_ne, w_ne);
  SPLAT(i_sw, w_sw);
  SPLAT(i_se, w_se);
#undef SPLAT
}

// Normalize: one thread per (b, p); handles the 3 output channels.
__global__ __launch_bounds__(256) void normalize_kernel(
    float* __restrict__ out, const float* __restrict__ dw_acc,
    const float* __restrict__ mask_acc) {
  int idx = blockIdx.x * blockDim.x + threadIdx.x;
  if (idx >= BB * HW) return;
  int b = idx / HW;
  int p = idx - b * HW;

  float m = mask_acc[b * HW + p];
  float dwv = dw_acc[b * HW + p];
  float inv = 1.0f / fmaxf(dwv, 1e-7f);
  bool invalid = (m < 0.5f);

  float* ob = out + (b * CC) * HW + p;
  for (int c = 0; c < CC; ++c) {
    float xw = ob[c * HW];
    ob[c * HW] = invalid ? 0.0f : xw * inv;
  }
}

extern "C" void kernel_launch(void* const* d_in, const int* in_sizes, int n_in,
                              void* d_out, int out_size, void* d_ws, size_t ws_size,
                              hipStream_t stream) {
  const float* x = (const float*)d_in[0];
  const float* flow = (const float*)d_in[1];
  const float* depth = (const float*)d_in[2];
  float* out = (float*)d_out;

  float* dw_acc = (float*)d_ws;            // [B, H, W]
  float* mask_acc = dw_acc + (size_t)BB * HW;  // [B, H, W]

  // Zero the accumulators (graph-capture-safe async memsets).
  hipMemsetAsync(d_out, 0, (size_t)BB * CC * HW * sizeof(float), stream);
  hipMemsetAsync(d_ws, 0, (size_t)2 * BB * HW * sizeof(float), stream);

  int n = BB * HW;
  int blocks = (n + 255) / 256;
  splat_kernel<<<blocks, 256, 0, stream>>>(x, flow, depth, out, dw_acc, mask_acc);
  normalize_kernel<<<blocks, 256, 0, stream>>>(out, dw_acc, mask_acc);
}

// Round 2
// 2766.632 us; speedup vs baseline: 1.2234x; 1.2234x over previous
//
#include <hip/hip_runtime.h>
#include <math.h>

// x [8,3,384,1280] f32, flow [8,2,384,1280] f32, depth [8,1,384,1280] f32
// -> out [8,3,384,1280] f32.
#define BB 8
#define CC 3
#define HH 384
#define WW 1280
#define HW (HH * WW)

// Target tiling for binned splat.
#define TILE 48
#define TW 49            // tile + 1 halo (NE/SW/SE corners)
#define TXN 27           // ceil(1280/48)
#define TYN 8            // 384/48
#define TILES (TXN * TYN)      // 216
#define BINS (BB * TILES)      // 1728
#define CAP 3072               // records per bin (expected ~2304)

// ---------------- fallback (round-1) path ----------------

__global__ __launch_bounds__(256) void splat_kernel(
    const float* __restrict__ x, const float* __restrict__ flow,
    const float* __restrict__ depth, float* __restrict__ xw_acc,
    float* __restrict__ dw_acc, float* __restrict__ mask_acc) {
  int idx = blockIdx.x * blockDim.x + threadIdx.x;
  if (idx >= BB * HW) return;
  int b = idx / HW;
  int p = idx - b * HW;
  int h = p / WW;
  int w = p - h * WW;

  float fx = flow[(b * 2 + 0) * HW + p];
  float fy = flow[(b * 2 + 1) * HW + p];
  fx = fminf(fmaxf(fx, -2.0f * WW), 2.0f * WW);
  fy = fminf(fmaxf(fy, -2.0f * WW), 2.0f * WW);

  float xs = fx + (float)w;
  float ys = fy + (float)h;
  float x0 = floorf(xs);
  float y0 = floorf(ys);
  if (!(x0 >= 0.0f && x0 <= (float)(WW - 2) && y0 >= 0.0f && y0 <= (float)(HH - 2)))
    return;
  int x0i = (int)x0;
  int y0i = (int)y0;
  float ax = xs - x0;
  float ay = ys - y0;
  float w_nw = (1.0f - ax) * (1.0f - ay);
  float w_ne = ax * (1.0f - ay);
  float w_sw = (1.0f - ax) * ay;
  float w_se = ax * ay;

  float d = depth[b * HW + p];
  d = fminf(fmaxf(d, 0.001f), 80.0f);
  float dw = expf(-(d - 40.0f) * (1.0f / 5.0f));

  float xv0 = x[(b * CC + 0) * HW + p] * dw;
  float xv1 = x[(b * CC + 1) * HW + p] * dw;
  float xv2 = x[(b * CC + 2) * HW + p] * dw;

  float* dwb = dw_acc + b * HW;
  float* mkb = mask_acc + b * HW;
  float* xb0 = xw_acc + (b * CC + 0) * HW;
  float* xb1 = xw_acc + (b * CC + 1) * HW;
  float* xb2 = xw_acc + (b * CC + 2) * HW;

  int i_nw = y0i * WW + x0i;
  int i_ne = i_nw + 1;
  int i_sw = i_nw + WW;
  int i_se = i_sw + 1;

#define SPLAT(ci, wt)                    \
  do {                                   \
    atomicAdd(dwb + (ci), (wt) * dw);    \
    atomicAdd(mkb + (ci), (wt));         \
    atomicAdd(xb0 + (ci), (wt) * xv0);   \
    atomicAdd(xb1 + (ci), (wt) * xv1);   \
    atomicAdd(xb2 + (ci), (wt) * xv2);   \
  } while (0)

  SPLAT(i_nw, w_nw);
  SPLAT(i_ne, w_ne);
  SPLAT(i_sw, w_sw);
  SPLAT(i_se, w_se);
#undef SPLAT
}

// ---------------- binned path ----------------

// Pass 1: compute validity + target tile, append source index to bin.
__global__ __launch_bounds__(256) void bin_kernel(
    const float* __restrict__ x, const float* __restrict__ flow,
    const float* __restrict__ depth, unsigned int* __restrict__ counts,
    unsigned int* __restrict__ records, float* __restrict__ xw_acc,
    float* __restrict__ dw_acc, float* __restrict__ mask_acc) {
  int idx = blockIdx.x * blockDim.x + threadIdx.x;
  if (idx >= BB * HW) return;
  int b = idx / HW;
  int p = idx - b * HW;
  int h = p / WW;
  int w = p - h * WW;

  float fx = flow[(b * 2 + 0) * HW + p];
  float fy = flow[(b * 2 + 1) * HW + p];
  fx = fminf(fmaxf(fx, -2.0f * WW), 2.0f * WW);
  fy = fminf(fmaxf(fy, -2.0f * WW), 2.0f * WW);

  float xs = fx + (float)w;
  float ys = fy + (float)h;
  float x0 = floorf(xs);
  float y0 = floorf(ys);
  if (!(x0 >= 0.0f && x0 <= (float)(WW - 2) && y0 >= 0.0f && y0 <= (float)(HH - 2)))
    return;
  int x0i = (int)x0;
  int y0i = (int)y0;
  int tx = x0i / TILE;
  int ty = y0i / TILE;
  int bin = b * TILES + ty * TXN + tx;

  unsigned int slot = atomicAdd(&counts[bin], 1u);
  if (slot < CAP) {
    records[(size_t)bin * CAP + slot] = (unsigned int)p;
    return;
  }

  // Overflow fallback: direct global atomics (additive, so compatible).
  float ax = xs - x0;
  float ay = ys - y0;
  float w_nw = (1.0f - ax) * (1.0f - ay);
  float w_ne = ax * (1.0f - ay);
  float w_sw = (1.0f - ax) * ay;
  float w_se = ax * ay;
  float d = depth[b * HW + p];
  d = fminf(fmaxf(d, 0.001f), 80.0f);
  float dw = expf(-(d - 40.0f) * (1.0f / 5.0f));
  float xv0 = x[(b * CC + 0) * HW + p] * dw;
  float xv1 = x[(b * CC + 1) * HW + p] * dw;
  float xv2 = x[(b * CC + 2) * HW + p] * dw;
  float* dwb = dw_acc + b * HW;
  float* mkb = mask_acc + b * HW;
  float* xb0 = xw_acc + (b * CC + 0) * HW;
  float* xb1 = xw_acc + (b * CC + 1) * HW;
  float* xb2 = xw_acc + (b * CC + 2) * HW;
  int i_nw = y0i * WW + x0i;
  int corner_i[4] = {i_nw, i_nw + 1, i_nw + WW, i_nw + WW + 1};
  float corner_w[4] = {w_nw, w_ne, w_sw, w_se};
  for (int c = 0; c < 4; ++c) {
    int ci = corner_i[c];
    float wt = corner_w[c];
    atomicAdd(dwb + ci, wt * dw);
    atomicAdd(mkb + ci, wt);
    atomicAdd(xb0 + ci, wt * xv0);
    atomicAdd(xb1 + ci, wt * xv1);
    atomicAdd(xb2 + ci, wt * xv2);
  }
}

// Pass 2: one workgroup per bin; LDS-accumulate the tile, then write back.
__global__ __launch_bounds__(256) void tile_splat_kernel(
    const float* __restrict__ x, const float* __restrict__ flow,
    const float* __restrict__ depth, const unsigned int* __restrict__ counts,
    const unsigned int* __restrict__ records, float* __restrict__ xw_acc,
    float* __restrict__ dw_acc, float* __restrict__ mask_acc) {
  __shared__ float acc[5][TW * TW];  // 5*2401*4 = 48020 B

  int bin = blockIdx.x;
  int b = bin / TILES;
  int t = bin - b * TILES;
  int ty = t / TXN;
  int tx = t - ty * TXN;
  int tid = threadIdx.x;

  for (int i = tid; i < 5 * TW * TW; i += 256)
    ((float*)acc)[i] = 0.0f;
  __syncthreads();

  unsigned int n = counts[bin];
  if (n > CAP) n = CAP;
  const unsigned int* rec = records + (size_t)bin * CAP;

  for (unsigned int r = tid; r < n; r += 256) {
    int p = (int)rec[r];
    int h = p / WW;
    int w = p - h * WW;

    float fx = flow[(b * 2 + 0) * HW + p];
    float fy = flow[(b * 2 + 1) * HW + p];
    fx = fminf(fmaxf(fx, -2.0f * WW), 2.0f * WW);
    fy = fminf(fmaxf(fy, -2.0f * WW), 2.0f * WW);
    float xs = fx + (float)w;
    float ys = fy + (float)h;
    float x0 = floorf(xs);
    float y0 = floorf(ys);
    int x0i = (int)x0;
    int y0i = (int)y0;
    int lx = x0i - tx * TILE;  // [0,47]
    int ly = y0i - ty * TILE;  // [0,47]
    float ax = xs - x0;
    float ay = ys - y0;
    float w_nw = (1.0f - ax) * (1.0f - ay);
    float w_ne = ax * (1.0f - ay);
    float w_sw = (1.0f - ax) * ay;
    float w_se = ax * ay;

    float d = depth[b * HW + p];
    d = fminf(fmaxf(d, 0.001f), 80.0f);
    float dw = expf(-(d - 40.0f) * (1.0f / 5.0f));
    float xv0 = x[(b * CC + 0) * HW + p] * dw;
    float xv1 = x[(b * CC + 1) * HW + p] * dw;
    float xv2 = x[(b * CC + 2) * HW + p] * dw;

    int li = ly * TW + lx;
    int ci[4] = {li, li + 1, li + TW, li + TW + 1};
    float cw[4] = {w_nw, w_ne, w_sw, w_se};
    for (int c = 0; c < 4; ++c) {
      atomicAdd(&acc[0][ci[c]], cw[c] * dw);
      atomicAdd(&acc[1][ci[c]], cw[c]);
      atomicAdd(&acc[2][ci[c]], cw[c] * xv0);
      atomicAdd(&acc[3][ci[c]], cw[c] * xv1);
      atomicAdd(&acc[4][ci[c]], cw[c] * xv2);
    }
  }
  __syncthreads();

  // Writeback. Cells with lx or ly in {0,48} are shared with neighbor tiles
  // (and the pass-1 overflow path) -> atomicAdd; interior cells are exclusive
  // to this block -> plain read-modify-write (accumulators were zeroed, and
  // pass 1 finished before pass 2 started).
  for (int i = tid; i < TW * TW; i += 256) {
    int ly = i / TW;
    int lx = i - ly * TW;
    int gy = ty * TILE + ly;
    int gx = tx * TILE + lx;
    if (gy >= HH || gx >= WW) continue;
    int g = gy * WW + gx;
    bool edge = (lx == 0) | (lx == TILE) | (ly == 0) | (ly == TILE);
    float v0 = acc[0][i];
    float v1 = acc[1][i];
    float v2 = acc[2][i];
    float v3 = acc[3][i];
    float v4 = acc[4][i];
    float* pdw = dw_acc + b * HW + g;
    float* pmk = mask_acc + b * HW + g;
    float* px0 = xw_acc + (b * CC + 0) * HW + g;
    float* px1 = xw_acc + (b * CC + 1) * HW + g;
    float* px2 = xw_acc + (b * CC + 2) * HW + g;
    if (edge) {
      if (v0 != 0.0f) atomicAdd(pdw, v0);
      if (v1 != 0.0f) atomicAdd(pmk, v1);
      if (v2 != 0.0f) atomicAdd(px0, v2);
      if (v3 != 0.0f) atomicAdd(px1, v3);
      if (v4 != 0.0f) atomicAdd(px2, v4);
    } else {
      *pdw += v0;
      *pmk += v1;
      *px0 += v2;
      *px1 += v3;
      *px2 += v4;
    }
  }
}

// Normalize: one thread per (b, p); handles the 3 output channels.
__global__ __launch_bounds__(256) void normalize_kernel(
    float* __restrict__ out, const float* __restrict__ dw_acc,
    const float* __restrict__ mask_acc) {
  int idx = blockIdx.x * blockDim.x + threadIdx.x;
  if (idx >= BB * HW) return;
  int b = idx / HW;
  int p = idx - b * HW;

  float m = mask_acc[b * HW + p];
  float dwv = dw_acc[b * HW + p];
  float inv = 1.0f / fmaxf(dwv, 1e-7f);
  bool invalid = (m < 0.5f);

  float* ob = out + (b * CC) * HW + p;
  for (int c = 0; c < CC; ++c) {
    float xw = ob[c * HW];
    ob[c * HW] = invalid ? 0.0f : xw * inv;
  }
}

extern "C" void kernel_launch(void* const* d_in, const int* in_sizes, int n_in,
                              void* d_out, int out_size, void* d_ws, size_t ws_size,
                              hipStream_t stream) {
  const float* x = (const float*)d_in[0];
  const float* flow = (const float*)d_in[1];
  const float* depth = (const float*)d_in[2];
  float* out = (float*)d_out;

  // ws layout: dw_acc [B*HW] f32 | mask_acc [B*HW] f32 | counts [BINS] u32 |
  //            records [BINS*CAP] u32
  float* dw_acc = (float*)d_ws;
  float* mask_acc = dw_acc + (size_t)BB * HW;
  unsigned int* counts = (unsigned int*)(mask_acc + (size_t)BB * HW);
  unsigned int* records = counts + BINS;

  size_t need = (size_t)2 * BB * HW * 4 + (size_t)BINS * 4 + (size_t)BINS * CAP * 4;

  int n = BB * HW;
  int blocks = (n + 255) / 256;

  hipMemsetAsync(d_out, 0, (size_t)BB * CC * HW * sizeof(float), stream);
  hipMemsetAsync(d_ws, 0, (size_t)2 * BB * HW * sizeof(float), stream);

  if (ws_size >= need) {
    hipMemsetAsync(counts, 0, (size_t)BINS * sizeof(unsigned int), stream);
    bin_kernel<<<blocks, 256, 0, stream>>>(x, flow, depth, counts, records,
                                           out, dw_acc, mask_acc);
    tile_splat_kernel<<<BINS, 256, 0, stream>>>(x, flow, depth, counts, records,
                                                out, dw_acc, mask_acc);
  } else {
    splat_kernel<<<blocks, 256, 0, stream>>>(x, flow, depth, out, dw_acc, mask_acc);
  }
  normalize_kernel<<<blocks, 256, 0, stream>>>(out, dw_acc, mask_acc);
}

// Round 3
// 492.900 us; speedup vs baseline: 6.8668x; 5.6130x over previous
//
#include <hip/hip_runtime.h>
#include <math.h>

// x [8,3,384,1280] f32, flow [8,2,384,1280] f32, depth [8,1,384,1280] f32
// -> out [8,3,384,1280] f32.
#define BB 8
#define CC 3
#define HH 384
#define WW 1280
#define HW (HH * WW)

// Target tiling for binned splat.
#define TILE 48
#define TW 49            // tile + 1 halo (NE/SW/SE corners)
#define TXN 27           // ceil(1280/48)
#define TYN 8            // 384/48
#define TILES (TXN * TYN)      // 216
#define BINS (BB * TILES)      // 1728
#define CAP 3072               // records per bin (expected ~2275)

// Binning kernel geometry.
#define BIN_PPT 16                       // pixels per thread
#define BIN_TPB 256                      // threads per block
#define BIN_PPB (BIN_PPT * BIN_TPB)      // 4096 pixels per block

// ---------------- fallback (round-1) path ----------------

__global__ __launch_bounds__(256) void splat_kernel(
    const float* __restrict__ x, const float* __restrict__ flow,
    const float* __restrict__ depth, float* __restrict__ xw_acc,
    float* __restrict__ dw_acc, float* __restrict__ mask_acc) {
  int idx = blockIdx.x * blockDim.x + threadIdx.x;
  if (idx >= BB * HW) return;
  int b = idx / HW;
  int p = idx - b * HW;
  int h = p / WW;
  int w = p - h * WW;

  float fx = flow[(b * 2 + 0) * HW + p];
  float fy = flow[(b * 2 + 1) * HW + p];
  fx = fminf(fmaxf(fx, -2.0f * WW), 2.0f * WW);
  fy = fminf(fmaxf(fy, -2.0f * WW), 2.0f * WW);

  float xs = fx + (float)w;
  float ys = fy + (float)h;
  float x0 = floorf(xs);
  float y0 = floorf(ys);
  if (!(x0 >= 0.0f && x0 <= (float)(WW - 2) && y0 >= 0.0f && y0 <= (float)(HH - 2)))
    return;
  int x0i = (int)x0;
  int y0i = (int)y0;
  float ax = xs - x0;
  float ay = ys - y0;
  float w_nw = (1.0f - ax) * (1.0f - ay);
  float w_ne = ax * (1.0f - ay);
  float w_sw = (1.0f - ax) * ay;
  float w_se = ax * ay;

  float d = depth[b * HW + p];
  d = fminf(fmaxf(d, 0.001f), 80.0f);
  float dw = expf(-(d - 40.0f) * (1.0f / 5.0f));

  float xv0 = x[(b * CC + 0) * HW + p] * dw;
  float xv1 = x[(b * CC + 1) * HW + p] * dw;
  float xv2 = x[(b * CC + 2) * HW + p] * dw;

  float* dwb = dw_acc + b * HW;
  float* mkb = mask_acc + b * HW;
  float* xb0 = xw_acc + (b * CC + 0) * HW;
  float* xb1 = xw_acc + (b * CC + 1) * HW;
  float* xb2 = xw_acc + (b * CC + 2) * HW;

  int i_nw = y0i * WW + x0i;
  int i_ne = i_nw + 1;
  int i_sw = i_nw + WW;
  int i_se = i_sw + 1;

#define SPLAT(ci, wt)                    \
  do {                                   \
    atomicAdd(dwb + (ci), (wt) * dw);    \
    atomicAdd(mkb + (ci), (wt));         \
    atomicAdd(xb0 + (ci), (wt) * xv0);   \
    atomicAdd(xb1 + (ci), (wt) * xv1);   \
    atomicAdd(xb2 + (ci), (wt) * xv2);   \
  } while (0)

  SPLAT(i_nw, w_nw);
  SPLAT(i_ne, w_ne);
  SPLAT(i_sw, w_sw);
  SPLAT(i_se, w_se);
#undef SPLAT
}

// ---------------- binned path ----------------

// Pass 1 (v2): block-aggregated binning. Each block handles BIN_PPB pixels:
//   A) LDS histogram over BINS,
//   B) one global returning atomicAdd per nonzero bin to reserve a range,
//   C) scatter records into reserved ranges via an LDS cursor.
// Global same-address atomics drop from ~3.9M to ~80K total.
__global__ __launch_bounds__(BIN_TPB) void bin_kernel(
    const float* __restrict__ x, const float* __restrict__ flow,
    const float* __restrict__ depth, unsigned int* __restrict__ counts,
    unsigned int* __restrict__ records, float* __restrict__ xw_acc,
    float* __restrict__ dw_acc, float* __restrict__ mask_acc) {
  __shared__ unsigned int cnt[BINS];   // 6912 B (histogram, then cursor)
  __shared__ unsigned int base[BINS];  // 6912 B

  int tid = threadIdx.x;
  int blk0 = blockIdx.x * BIN_PPB;

  for (int i = tid; i < BINS; i += BIN_TPB) cnt[i] = 0u;
  __syncthreads();

  int binr[BIN_PPT];

  // Phase A: compute bins, LDS histogram.
#pragma unroll
  for (int k = 0; k < BIN_PPT; ++k) {
    int idx = blk0 + k * BIN_TPB + tid;
    int bin = -1;
    if (idx < BB * HW) {
      int b = idx / HW;
      int p = idx - b * HW;
      int h = p / WW;
      int w = p - h * WW;
      float fx = flow[(b * 2 + 0) * HW + p];
      float fy = flow[(b * 2 + 1) * HW + p];
      fx = fminf(fmaxf(fx, -2.0f * WW), 2.0f * WW);
      fy = fminf(fmaxf(fy, -2.0f * WW), 2.0f * WW);
      float xs = fx + (float)w;
      float ys = fy + (float)h;
      float x0 = floorf(xs);
      float y0 = floorf(ys);
      if (x0 >= 0.0f && x0 <= (float)(WW - 2) && y0 >= 0.0f &&
          y0 <= (float)(HH - 2)) {
        int tx = (int)x0 / TILE;
        int ty = (int)y0 / TILE;
        bin = b * TILES + ty * TXN + tx;
        atomicAdd(&cnt[bin], 1u);
      }
    }
    binr[k] = bin;
  }
  __syncthreads();

  // Phase B: reserve global ranges; reset LDS counters for cursor use.
  for (int i = tid; i < BINS; i += BIN_TPB) {
    unsigned int c = cnt[i];
    if (c) {
      base[i] = atomicAdd(&counts[i], c);
      cnt[i] = 0u;
    }
  }
  __syncthreads();

  // Phase C: write records (or rare overflow fallback -> direct atomics).
#pragma unroll
  for (int k = 0; k < BIN_PPT; ++k) {
    int bin = binr[k];
    if (bin < 0) continue;
    int idx = blk0 + k * BIN_TPB + tid;
    unsigned int off = atomicAdd(&cnt[bin], 1u);
    unsigned int slot = base[bin] + off;
    int b = idx / HW;
    int p = idx - b * HW;
    if (slot < CAP) {
      records[(size_t)bin * CAP + slot] = (unsigned int)p;
      continue;
    }
    // Overflow fallback (additive, sequenced before tile_splat).
    int h = p / WW;
    int w = p - h * WW;
    float fx = flow[(b * 2 + 0) * HW + p];
    float fy = flow[(b * 2 + 1) * HW + p];
    fx = fminf(fmaxf(fx, -2.0f * WW), 2.0f * WW);
    fy = fminf(fmaxf(fy, -2.0f * WW), 2.0f * WW);
    float xs = fx + (float)w;
    float ys = fy + (float)h;
    float x0 = floorf(xs);
    float y0 = floorf(ys);
    int x0i = (int)x0;
    int y0i = (int)y0;
    float ax = xs - x0;
    float ay = ys - y0;
    float w_nw = (1.0f - ax) * (1.0f - ay);
    float w_ne = ax * (1.0f - ay);
    float w_sw = (1.0f - ax) * ay;
    float w_se = ax * ay;
    float d = depth[b * HW + p];
    d = fminf(fmaxf(d, 0.001f), 80.0f);
    float dw = expf(-(d - 40.0f) * (1.0f / 5.0f));
    float xv0 = x[(b * CC + 0) * HW + p] * dw;
    float xv1 = x[(b * CC + 1) * HW + p] * dw;
    float xv2 = x[(b * CC + 2) * HW + p] * dw;
    float* dwb = dw_acc + b * HW;
    float* mkb = mask_acc + b * HW;
    float* xb0 = xw_acc + (b * CC + 0) * HW;
    float* xb1 = xw_acc + (b * CC + 1) * HW;
    float* xb2 = xw_acc + (b * CC + 2) * HW;
    int i_nw = y0i * WW + x0i;
    int corner_i[4] = {i_nw, i_nw + 1, i_nw + WW, i_nw + WW + 1};
    float corner_w[4] = {w_nw, w_ne, w_sw, w_se};
    for (int c = 0; c < 4; ++c) {
      int ci = corner_i[c];
      float wt = corner_w[c];
      atomicAdd(dwb + ci, wt * dw);
      atomicAdd(mkb + ci, wt);
      atomicAdd(xb0 + ci, wt * xv0);
      atomicAdd(xb1 + ci, wt * xv1);
      atomicAdd(xb2 + ci, wt * xv2);
    }
  }
}

// Pass 2: one workgroup per bin; LDS-accumulate the tile, then write back.
__global__ __launch_bounds__(256) void tile_splat_kernel(
    const float* __restrict__ x, const float* __restrict__ flow,
    const float* __restrict__ depth, const unsigned int* __restrict__ counts,
    const unsigned int* __restrict__ records, float* __restrict__ xw_acc,
    float* __restrict__ dw_acc, float* __restrict__ mask_acc) {
  __shared__ float acc[5][TW * TW];  // 5*2401*4 = 48020 B

  int bin = blockIdx.x;
  int b = bin / TILES;
  int t = bin - b * TILES;
  int ty = t / TXN;
  int tx = t - ty * TXN;
  int tid = threadIdx.x;

  for (int i = tid; i < 5 * TW * TW; i += 256)
    ((float*)acc)[i] = 0.0f;
  __syncthreads();

  unsigned int n = counts[bin];
  if (n > CAP) n = CAP;
  const unsigned int* rec = records + (size_t)bin * CAP;

  for (unsigned int r = tid; r < n; r += 256) {
    int p = (int)rec[r];
    int h = p / WW;
    int w = p - h * WW;

    float fx = flow[(b * 2 + 0) * HW + p];
    float fy = flow[(b * 2 + 1) * HW + p];
    fx = fminf(fmaxf(fx, -2.0f * WW), 2.0f * WW);
    fy = fminf(fmaxf(fy, -2.0f * WW), 2.0f * WW);
    float xs = fx + (float)w;
    float ys = fy + (float)h;
    float x0 = floorf(xs);
    float y0 = floorf(ys);
    int x0i = (int)x0;
    int y0i = (int)y0;
    int lx = x0i - tx * TILE;  // [0,47]
    int ly = y0i - ty * TILE;  // [0,47]
    float ax = xs - x0;
    float ay = ys - y0;
    float w_nw = (1.0f - ax) * (1.0f - ay);
    float w_ne = ax * (1.0f - ay);
    float w_sw = (1.0f - ax) * ay;
    float w_se = ax * ay;

    float d = depth[b * HW + p];
    d = fminf(fmaxf(d, 0.001f), 80.0f);
    float dw = expf(-(d - 40.0f) * (1.0f / 5.0f));
    float xv0 = x[(b * CC + 0) * HW + p] * dw;
    float xv1 = x[(b * CC + 1) * HW + p] * dw;
    float xv2 = x[(b * CC + 2) * HW + p] * dw;

    int li = ly * TW + lx;
    int ci[4] = {li, li + 1, li + TW, li + TW + 1};
    float cw[4] = {w_nw, w_ne, w_sw, w_se};
    for (int c = 0; c < 4; ++c) {
      atomicAdd(&acc[0][ci[c]], cw[c] * dw);
      atomicAdd(&acc[1][ci[c]], cw[c]);
      atomicAdd(&acc[2][ci[c]], cw[c] * xv0);
      atomicAdd(&acc[3][ci[c]], cw[c] * xv1);
      atomicAdd(&acc[4][ci[c]], cw[c] * xv2);
    }
  }
  __syncthreads();

  // Writeback. Cells with lx or ly in {0,48} are shared with neighbor tiles
  // (and the overflow path) -> atomicAdd; interior cells are exclusive to
  // this block -> plain read-modify-write.
  for (int i = tid; i < TW * TW; i += 256) {
    int ly = i / TW;
    int lx = i - ly * TW;
    int gy = ty * TILE + ly;
    int gx = tx * TILE + lx;
    if (gy >= HH || gx >= WW) continue;
    int g = gy * WW + gx;
    bool edge = (lx == 0) | (lx == TILE) | (ly == 0) | (ly == TILE);
    float v0 = acc[0][i];
    float v1 = acc[1][i];
    float v2 = acc[2][i];
    float v3 = acc[3][i];
    float v4 = acc[4][i];
    float* pdw = dw_acc + b * HW + g;
    float* pmk = mask_acc + b * HW + g;
    float* px0 = xw_acc + (b * CC + 0) * HW + g;
    float* px1 = xw_acc + (b * CC + 1) * HW + g;
    float* px2 = xw_acc + (b * CC + 2) * HW + g;
    if (edge) {
      if (v0 != 0.0f) atomicAdd(pdw, v0);
      if (v1 != 0.0f) atomicAdd(pmk, v1);
      if (v2 != 0.0f) atomicAdd(px0, v2);
      if (v3 != 0.0f) atomicAdd(px1, v3);
      if (v4 != 0.0f) atomicAdd(px2, v4);
    } else {
      *pdw += v0;
      *pmk += v1;
      *px0 += v2;
      *px1 += v3;
      *px2 += v4;
    }
  }
}

// Normalize: one thread per (b, p); handles the 3 output channels.
__global__ __launch_bounds__(256) void normalize_kernel(
    float* __restrict__ out, const float* __restrict__ dw_acc,
    const float* __restrict__ mask_acc) {
  int idx = blockIdx.x * blockDim.x + threadIdx.x;
  if (idx >= BB * HW) return;
  int b = idx / HW;
  int p = idx - b * HW;

  float m = mask_acc[b * HW + p];
  float dwv = dw_acc[b * HW + p];
  float inv = 1.0f / fmaxf(dwv, 1e-7f);
  bool invalid = (m < 0.5f);

  float* ob = out + (b * CC) * HW + p;
  for (int c = 0; c < CC; ++c) {
    float xw = ob[c * HW];
    ob[c * HW] = invalid ? 0.0f : xw * inv;
  }
}

extern "C" void kernel_launch(void* const* d_in, const int* in_sizes, int n_in,
                              void* d_out, int out_size, void* d_ws, size_t ws_size,
                              hipStream_t stream) {
  const float* x = (const float*)d_in[0];
  const float* flow = (const float*)d_in[1];
  const float* depth = (const float*)d_in[2];
  float* out = (float*)d_out;

  // ws layout: dw_acc [B*HW] f32 | mask_acc [B*HW] f32 | counts [BINS] u32 |
  //            records [BINS*CAP] u32
  float* dw_acc = (float*)d_ws;
  float* mask_acc = dw_acc + (size_t)BB * HW;
  unsigned int* counts = (unsigned int*)(mask_acc + (size_t)BB * HW);
  unsigned int* records = counts + BINS;

  size_t need = (size_t)2 * BB * HW * 4 + (size_t)BINS * 4 + (size_t)BINS * CAP * 4;

  int n = BB * HW;
  int blocks = (n + 255) / 256;

  hipMemsetAsync(d_out, 0, (size_t)BB * CC * HW * sizeof(float), stream);
  hipMemsetAsync(d_ws, 0, (size_t)2 * BB * HW * sizeof(float), stream);

  if (ws_size >= need) {
    hipMemsetAsync(counts, 0, (size_t)BINS * sizeof(unsigned int), stream);
    int bin_blocks = (n + BIN_PPB - 1) / BIN_PPB;  // 960
    bin_kernel<<<bin_blocks, BIN_TPB, 0, stream>>>(x, flow, depth, counts,
                                                   records, out, dw_acc,
                                                   mask_acc);
    tile_splat_kernel<<<BINS, 256, 0, stream>>>(x, flow, depth, counts, records,
                                                out, dw_acc, mask_acc);
  } else {
    splat_kernel<<<blocks, 256, 0, stream>>>(x, flow, depth, out, dw_acc, mask_acc);
  }
  normalize_kernel<<<blocks, 256, 0, stream>>>(out, dw_acc, mask_acc);
}